// Round 4
// baseline (173.908 us; speedup 1.0000x reference)
//
#include <hip/hip_runtime.h>

#define SQL  1024
#define EDIM 256
#define NHD  8
#define NKV  (NHD * 3 * EDIM)   // 6144
#define MROWS (4 * SQL)         // 4096

typedef short bf16x8 __attribute__((ext_vector_type(8)));
typedef float f32x4 __attribute__((ext_vector_type(4)));

__device__ __forceinline__ unsigned short f2bf(float f) {
  unsigned u = __float_as_uint(f);
  u += 0x7fff + ((u >> 16) & 1);   // round-to-nearest-even (finite values)
  return (unsigned short)(u >> 16);
}

// async 16B global->LDS (direct-to-shared DMA; LDS dest must be
// wave-uniform base + lane*16 — all call sites use flat (it*T+tid)*16B)
__device__ __forceinline__ void g2lds16(const void* g, void* l) {
  __builtin_amdgcn_global_load_lds(
      (const __attribute__((address_space(1))) unsigned int*)g,
      (__attribute__((address_space(3))) unsigned int*)l, 16, 0, 0);
}

__device__ __forceinline__ void storev(float* p, float v) { *p = v; }
__device__ __forceinline__ void storev(unsigned short* p, float v) { *p = f2bf(v); }

// =====================================================================
// fused fp32 -> bf16 cast for all three inputs, 8 elems/thread.
// =====================================================================
__global__ __launch_bounds__(256) void cast3_bf16(
    const float* __restrict__ s0, unsigned short* __restrict__ d0, int n0,
    const float* __restrict__ s1, unsigned short* __restrict__ d1, int n1,
    const float* __restrict__ s2, unsigned short* __restrict__ d2, int n2) {
  int i = blockIdx.x * 256 + threadIdx.x;
  const float* s; unsigned short* d;
  if (i < n0) { s = s0; d = d0; }
  else if (i < n0 + n1) { i -= n0; s = s1; d = d1; }
  else { i -= n0 + n1; if (i >= n2) return; s = s2; d = d2; }
  float4 a = ((const float4*)s)[2 * i];
  float4 b = ((const float4*)s)[2 * i + 1];
  union { unsigned short u[8]; ulonglong2 v; } t;
  t.u[0] = f2bf(a.x); t.u[1] = f2bf(a.y); t.u[2] = f2bf(a.z); t.u[3] = f2bf(a.w);
  t.u[4] = f2bf(b.x); t.u[5] = f2bf(b.y); t.u[6] = f2bf(b.z); t.u[7] = f2bf(b.w);
  ((ulonglong2*)d)[i] = t.v;
}

// =====================================================================
// bf16 MFMA NT-GEMM, double-buffered global_load_lds staging.
// (round-0 proven version)
// =====================================================================
template <int BM, int BN, typename OutT>
__global__ __launch_bounds__(256) void gemm_mfma(
    const unsigned short* __restrict__ A, const unsigned short* __restrict__ B,
    const float* __restrict__ bias, OutT* __restrict__ C,
    int M, int N, int K) {
  constexpr int TM = BM / 32, TN = BN / 32;
  __shared__ __align__(16) unsigned short As[2][BM * 32];
  __shared__ __align__(16) unsigned short Bs[2][BN * 32];
  const int tid = threadIdx.x;
  const int wave = tid >> 6, lane = tid & 63;
  const int quad = lane >> 4, l16 = lane & 15;
  const int wm = (wave >> 1) * (BM / 2), wn = (wave & 1) * (BN / 2);
  const int m0 = blockIdx.x * BM, n0 = blockIdx.y * BN;
  const int sw = (l16 >> 1) & 3;

  f32x4 acc[TM][TN];
  #pragma unroll
  for (int i = 0; i < TM; i++)
    #pragma unroll
    for (int j = 0; j < TN; j++) acc[i][j] = {0.f, 0.f, 0.f, 0.f};

  auto stage = [&](int k0, int bb) {
    #pragma unroll
    for (int it = 0; it < BM / 64; it++) {
      int flat = it * 256 + tid;
      int row = flat >> 2;
      int cg = (flat & 3) ^ ((row >> 1) & 3);
      g2lds16(A + (size_t)(m0 + row) * K + k0 + cg * 8, &As[bb][flat * 8]);
    }
    #pragma unroll
    for (int it = 0; it < BN / 64; it++) {
      int flat = it * 256 + tid;
      int row = flat >> 2;
      int cg = (flat & 3) ^ ((row >> 1) & 3);
      g2lds16(B + (size_t)(n0 + row) * K + k0 + cg * 8, &Bs[bb][flat * 8]);
    }
  };

  stage(0, 0);
  __syncthreads();
  for (int k0 = 0; k0 < K; k0 += 32) {
    const int bb = (k0 >> 5) & 1;
    if (k0 + 32 < K) stage(k0 + 32, bb ^ 1);
    bf16x8 af[TM], bf[TN];
    #pragma unroll
    for (int i = 0; i < TM; i++)
      af[i] = *(const bf16x8*)&As[bb][(wm + i * 16 + l16) * 32 + (quad ^ sw) * 8];
    #pragma unroll
    for (int j = 0; j < TN; j++)
      bf[j] = *(const bf16x8*)&Bs[bb][(wn + j * 16 + l16) * 32 + (quad ^ sw) * 8];
    #pragma unroll
    for (int i = 0; i < TM; i++)
      #pragma unroll
      for (int j = 0; j < TN; j++)
        acc[i][j] = __builtin_amdgcn_mfma_f32_16x16x32_bf16(af[i], bf[j], acc[i][j], 0, 0, 0);
    __syncthreads();  // gates buffer reuse + drains this iter's prefetch
  }

  #pragma unroll
  for (int i = 0; i < TM; i++) {
    #pragma unroll
    for (int r = 0; r < 4; r++) {
      int m = m0 + wm + i * 16 + quad * 4 + r;
      #pragma unroll
      for (int j = 0; j < TN; j++) {
        int n = n0 + wn + j * 16 + l16;
        storev(&C[(size_t)m * N + n], acc[i][j][r] + bias[n]);
      }
    }
  }
}

// =====================================================================
// V transpose, kt-tile-major output with baked-in chunk swizzle:
// vt_tiled[bh][t=s/32][d][cj] (cj = 16B chunk) where chunk (d, j) of
// Vt[d][k=j*8..+7] lands at cj = j ^ ((d>>1)&3). Staging a kt tile is
// then one contiguous 16KB linear DMA, and the PV LDS read
// VtB[d*32 + (quad^((d>>1)&3))*8] is bank-conflict-free (8 distinct
// 16B slots per 8-lane group; was 4-way with the old layout).
// =====================================================================
__global__ __launch_bounds__(256) void transpose_v(
    const unsigned short* __restrict__ proj, unsigned short* __restrict__ vt) {
  __shared__ unsigned short T[64][66];
  const int tid = threadIdx.x;
  const int s0 = blockIdx.x * 64, d0 = blockIdx.y * 64, bh = blockIdx.z;
  const int b = bh >> 3, h = bh & 7;
  #pragma unroll
  for (int it = 0; it < 2; it++) {
    int c = it * 256 + tid;
    int sr = c >> 3, k8 = (c & 7) * 8;
    int s = s0 + sr;
    const unsigned short* src = proj + (size_t)(b * SQL + h * 128 + (s >> 3)) * NKV
                                + 2 * 2048 + (s & 7) * 256 + d0 + k8;
    *(ulonglong2*)&T[sr][k8] = *(const ulonglong2*)src;
  }
  __syncthreads();
  #pragma unroll
  for (int it = 0; it < 2; it++) {
    int c = it * 256 + tid;
    int dr = c >> 3, s8 = (c & 7) * 8;
    unsigned short tmp[8];
    #pragma unroll
    for (int j = 0; j < 8; j++) tmp[j] = T[s8 + j][dr];
    const int d = d0 + dr;
    const int t = (s0 + s8) >> 5;          // kt tile index 0..31
    const int j = (s8 >> 3) & 3;           // k-chunk within tile
    const int cj = j ^ ((d >> 1) & 3);     // baked swizzle
    unsigned short* dst = vt + (((size_t)bh * 32 + t) * 1024 + d * 4 + cj) * 8;
    *(ulonglong2*)dst = *(ulonglong2*)tmp;
  }
}

// =====================================================================
// bf16 MFMA flash attention, round 7: parity-kt split.
// R3 showed 8 waves buy +33% issue rate but duplicated QK cost 1.5x
// work (47*1.5/1.33 = 53.3 measured). This keeps the 8 waves at 1.0x
// work: wave (qs, p) is EXACTLY an R0 wave (16 q-rows, full 32 k, full
// 256 d, o[16], private softmax+Ps) but handles only kt tiles with
// kt&1 == p. One barrier per 2 kt (half of R0), full wave independence
// between barriers (R1 lesson), no duplication (R3 lesson). Cross-
// parity o/l summed once in epilogue via LDS (buffers dead by then).
// Vt conflict fix: tile-major vt with baked swizzle -> PV reads
// conflict-free (was 4-way = ~535 cyc/iter of the ~3300 cyc budget).
// LDS: 2 pair-buffers (K.even|K.odd|V.even|V.odd = 64KB) = 128KB
// + Ps 8x[16][40] 10KB = 138KB -> 1 block/CU, 8 waves = 2/SIMD.
// =====================================================================
__global__ __launch_bounds__(512, 2) void attn_mfma(
    const unsigned short* __restrict__ proj,
    const unsigned short* __restrict__ vt,
    unsigned short* __restrict__ oflat) {
  // shorts: buf0 @0 (32768: K0 8192|K1 8192|V0 8192|V1 8192) | buf1 @32768 | Ps @65536 (5120)
  __shared__ __align__(16) unsigned short lds[70656];
  __shared__ float lsumX[4][16];
  unsigned short* Ps = lds + 65536;  // 8 slices x [16][40]

  const int tid = threadIdx.x;          // 0..511
  const int wave = tid >> 6, lane = tid & 63;
  const int quad = lane >> 4, l16 = lane & 15;
  const int qs = wave >> 1;             // q-row subtile: rows qs*16..+15
  const int p  = wave & 1;              // kt parity
  // balanced decode: slot s -> (bh = s&31, j = s>>5); round 0 heavy, 1 light
  const int slot = blockIdx.x & 255, round = blockIdx.x >> 8;
  const int bh = slot & 31;
  const int jj = slot >> 5;
  const int qt = round ? jj : 15 - jj;
  const int b = bh >> 3, h = bh & 7;
  const int q0 = qt * 64;

  auto stagepair = [&](int pr, int bb) {
    unsigned short* B = lds + bb * 32768;
    #pragma unroll
    for (int it = 0; it < 4; it++) {   // K tiles 2pr, 2pr+1: 64 rows x 256
      int c = it * 512 + tid;
      int r = c >> 5, ch = (c & 31) ^ (r & 7);
      int s = pr * 64 + r;
      g2lds16(proj + (size_t)(b * SQL + h * 128 + (s >> 3)) * NKV + 2048 + (s & 7) * 256 + ch * 8,
              B + c * 8);
    }
    const unsigned short* vsrc = vt + ((size_t)bh * 32 + pr * 2) * 8192;
    #pragma unroll
    for (int it = 0; it < 4; it++) {   // V tiles 2pr, 2pr+1: contiguous 32KB
      int c = it * 512 + tid;
      g2lds16(vsrc + c * 8, B + 16384 + c * 8);
    }
  };

  // ---- prologue: pair 0 -> buf0, Q (64x256) -> buf1, one drain ----
  stagepair(0, 0);
  #pragma unroll
  for (int it = 0; it < 4; it++) {
    int c = it * 512 + tid;
    int r = c >> 5, ch = (c & 31) ^ (r & 7);
    int s = q0 + r;
    g2lds16(proj + (size_t)(b * SQL + h * 128 + (s >> 3)) * NKV + (s & 7) * 256 + ch * 8,
            lds + 32768 + c * 8);
  }
  __syncthreads();
  bf16x8 aq[8];
  const int qrow = qs * 16 + l16;
  #pragma unroll
  for (int kk = 0; kk < 8; kk++)
    aq[kk] = *(const bf16x8*)&lds[32768 + qrow * 256 + ((kk * 4 + quad) ^ (qrow & 7)) * 8];
  __syncthreads();  // all waves done reading Q before buf1 overwrite

  f32x4 o[16];
  #pragma unroll
  for (int t = 0; t < 16; t++) o[t] = {0.f, 0.f, 0.f, 0.f};
  float l_r[4] = {0.f, 0.f, 0.f, 0.f};

  const int np = qt + 1;   // pairs of kt tiles
  for (int pr = 0; pr < np; pr++) {
    const int bb = pr & 1;
    if (pr + 1 < np) stagepair(pr + 1, bb ^ 1);  // prefetch into other buffer
    unsigned short* B = lds + bb * 32768;
    const unsigned short* KsB = B + p * 8192;            // my parity's K tile
    const unsigned short* VtB = B + 16384 + p * 8192;    // my parity's V tile
    const int my_kt = 2 * pr + p;
    // masked-out waves (diagonal pair, low qs on odd parity) skip compute
    const bool live = (my_kt * 32 <= q0 + qs * 16 + 15);

    if (live) {
      // ---- S = Q K^T (two 16-col tiles), full 32 k-cols per wave ----
      f32x4 s0 = {0.f, 0.f, 0.f, 0.f}, s1 = {0.f, 0.f, 0.f, 0.f};
      #pragma unroll
      for (int kk = 0; kk < 8; kk++) {
        int ch = (kk * 4 + quad) ^ (l16 & 7);
        bf16x8 b0 = *(const bf16x8*)&KsB[l16 * 256 + ch * 8];
        bf16x8 b1 = *(const bf16x8*)&KsB[(16 + l16) * 256 + ch * 8];
        s0 = __builtin_amdgcn_mfma_f32_16x16x32_bf16(aq[kk], b0, s0, 0, 0, 0);
        s1 = __builtin_amdgcn_mfma_f32_16x16x32_bf16(aq[kk], b1, s1, 0, 0, 0);
      }

      // ---- shift-free softmax: p = exp2(s/16*log2e), lane-local l ----
      const int kg0 = my_kt * 32 + l16, kg1 = kg0 + 16;
      unsigned short* PsW = Ps + wave * 640;  // private [16][40] slice
      #pragma unroll
      for (int r = 0; r < 4; r++) {
        int qg = q0 + qs * 16 + quad * 4 + r;
        float p0 = (kg0 <= qg) ? exp2f(s0[r] * 0.09016844f) : 0.f;
        float p1 = (kg1 <= qg) ? exp2f(s1[r] * 0.09016844f) : 0.f;
        l_r[r] += p0 + p1;
        PsW[(quad * 4 + r) * 40 + l16]      = f2bf(p0);
        PsW[(quad * 4 + r) * 40 + 16 + l16] = f2bf(p1);
      }

      // ---- PV, full 256 d: conflict-free Vt reads (baked swizzle) ----
      bf16x8 ap = *(const bf16x8*)&PsW[l16 * 40 + quad * 8];
      #pragma unroll
      for (int tl = 0; tl < 16; tl++) {
        const int d = tl * 16 + l16;
        bf16x8 bv = *(const bf16x8*)&VtB[d * 32 + (quad ^ ((d >> 1) & 3)) * 8];
        o[tl] = __builtin_amdgcn_mfma_f32_16x16x32_bf16(ap, bv, o[tl], 0, 0, 0);
      }
    }
    __syncthreads();  // buffer reuse gate + drains this iter's prefetch
  }

  // ---- epilogue: wave-local l reduce, cross-parity o/l sum, scatter ----
  float lr[4];
  #pragma unroll
  for (int r = 0; r < 4; r++) {
    float l = l_r[r];
    #pragma unroll
    for (int off = 1; off < 16; off <<= 1) l += __shfl_xor(l, off);
    lr[r] = l;
  }
  if (p == 1) {
    f32x4* ob = (f32x4*)lds;   // 4 qs x 16 t x 64 lanes x 16B = 64KB (buf space, dead)
    #pragma unroll
    for (int t = 0; t < 16; t++) ob[(qs * 16 + t) * 64 + lane] = o[t];
    if (l16 == 0) {
      #pragma unroll
      for (int r = 0; r < 4; r++) lsumX[qs][quad * 4 + r] = lr[r];
    }
  }
  __syncthreads();
  if (p == 0) {
    const f32x4* ob = (const f32x4*)lds;
    #pragma unroll
    for (int t = 0; t < 16; t++) o[t] += ob[(qs * 16 + t) * 64 + lane];
    float inv[4];
    #pragma unroll
    for (int r = 0; r < 4; r++) inv[r] = 1.0f / (lr[r] + lsumX[qs][quad * 4 + r]);
    #pragma unroll
    for (int r = 0; r < 4; r++) {
      int s = q0 + qs * 16 + quad * 4 + r;
      unsigned short* dst = oflat + (size_t)(b * SQL + h * 128 + (s >> 3)) * 2048 + (s & 7) * 256;
      #pragma unroll
      for (int t = 0; t < 16; t++)
        dst[t * 16 + l16] = f2bf(o[t][r] * inv[r]);
    }
  }
}

extern "C" void kernel_launch(void* const* d_in, const int* in_sizes, int n_in,
                              void* d_out, int out_size, void* d_ws, size_t ws_size,
                              hipStream_t stream) {
  const float* x      = (const float*)d_in[0];
  const float* w_attn = (const float*)d_in[1];
  const float* b_attn = (const float*)d_in[2];
  const float* w_out  = (const float*)d_in[3];
  const float* b_out  = (const float*)d_in[4];
  float* out = (float*)d_out;

  char* p = (char*)d_ws;
  unsigned short* proj = (unsigned short*)p;  p += (size_t)MROWS * NKV * 2;
  unsigned short* obf  = (unsigned short*)p;  p += (size_t)MROWS * 2048 * 2;
  unsigned short* vtb  = (unsigned short*)p;  p += (size_t)32 * EDIM * SQL * 2;
  unsigned short* xb   = (unsigned short*)p;  p += (size_t)MROWS * EDIM * 2;
  unsigned short* wb   = (unsigned short*)p;  p += (size_t)NKV * EDIM * 2;
  unsigned short* wob  = (unsigned short*)p;

  const int n0 = MROWS * EDIM / 8;        // 131072 -> 512 blocks
  const int n1 = NKV * EDIM / 8;          // 196608 -> 768 blocks
  const int n2 = EDIM * 2048 / 8;         // 65536  -> 256 blocks
  cast3_bf16<<<(n0 + n1 + n2) / 256, 256, 0, stream>>>(x, xb, n0, w_attn, wb, n1,
                                                       w_out, wob, n2);

  gemm_mfma<128, 128, unsigned short><<<dim3(MROWS / 128, NKV / 128), 256, 0, stream>>>(
      xb, wb, b_attn, proj, MROWS, NKV, EDIM);
  transpose_v<<<dim3(SQL / 64, EDIM / 64, 32), 256, 0, stream>>>(proj, vtb);
  attn_mfma<<<512, 512, 0, stream>>>(proj, vtb, obf);
  gemm_mfma<64, 64, float><<<dim3(MROWS / 64, EDIM / 64), 256, 0, stream>>>(
      obf, wob, b_out, out, MROWS, EDIM, NHD * EDIM);
}